// Round 3
// baseline (3576.787 us; speedup 1.0000x reference)
//
#include <hip/hip_runtime.h>

// DGCNN forward, fp32 throughout.
// R3: (a) bank-conflict-free GEMM micro-tiles (LDS stride 132, split 4+4 column
// groups at tx*4 / 64+tx*4); (b) symmetric distance GEMM computes only bi<=bj
// tiles and mirror-writes the transpose (halves dgemm FLOPs).

#define NPTS   4096
#define NB     8
#define BNR    32768      // NB*NPTS
#define KNN    20
#define EPSBN  1e-5f

__device__ __forceinline__ float lrelu(float x){ return x > 0.f ? x : 0.2f*x; }

// x (8,6,4096) -> xt (8,4096,8), channels 6,7 zero-padded
__global__ __launch_bounds__(256) void k_transpose_pad(const float* __restrict__ x,
                                                       float* __restrict__ xt){
  int id = blockIdx.x*256 + threadIdx.x;          // 0..32767
  int b = id >> 12, n = id & (NPTS-1);
  const float* xb = x + (size_t)b*6*NPTS + n;
  float* o = xt + (size_t)id*8;
#pragma unroll
  for (int c = 0; c < 6; ++c) o[c] = xb[(size_t)c*NPTS];
  o[6] = 0.f; o[7] = 0.f;
}

// squared norm per row (c4 float4 groups, row stride xstride floats)
__global__ __launch_bounds__(256) void k_sqnorm(const float* __restrict__ X, int xstride, int c4,
                                                float* __restrict__ sq){
  int id = blockIdx.x*256 + threadIdx.x;
  const float4* r = (const float4*)(X + (size_t)id*xstride);
  float s = 0.f;
  for (int c = 0; c < c4; ++c){ float4 v = r[c]; s += v.x*v.x + v.y*v.y + v.z*v.z + v.w*v.w; }
  sq[id] = s;
}

// D[i][j] = 2*dot(x_i,x_j) - sq_i - sq_j, one batch, symmetric: only bi<=bj tiles
// computed; off-diagonal tiles mirror-store the transpose. 128x128 tile, 8x8 micro
// (rows ty*8+r; cols tx*4+c and 64+tx*4+c).
__global__ __launch_bounds__(256) void k_dgemm(const float* __restrict__ X, int xstride, int Kdim,
                                               const float* __restrict__ sqv,
                                               float* __restrict__ D){
  const int bi = blockIdx.y, bj = blockIdx.x;
  if (bj < bi) return;
  __shared__ float As[16][132];
  __shared__ float Bs[16][132];
  const int i0 = bi*128, j0 = bj*128;
  const int tid = threadIdx.x, tx = tid & 15, ty = tid >> 4;
  float acc[8][8] = {};
  for (int k0 = 0; k0 < Kdim; k0 += 16){
#pragma unroll
    for (int i = 0; i < 8; ++i){
      int li = tid + 256*i;
      int row = li >> 4, kk = li & 15;
      bool ok = (k0 + kk) < Kdim;
      As[kk][row] = ok ? X[(size_t)(i0+row)*xstride + k0+kk] : 0.f;
      Bs[kk][row] = ok ? X[(size_t)(j0+row)*xstride + k0+kk] : 0.f;
    }
    __syncthreads();
#pragma unroll
    for (int kk = 0; kk < 16; ++kk){
      float a[8], b[8];
      *(float4*)&a[0] = *(const float4*)&As[kk][ty*8];
      *(float4*)&a[4] = *(const float4*)&As[kk][ty*8+4];
      *(float4*)&b[0] = *(const float4*)&Bs[kk][tx*4];
      *(float4*)&b[4] = *(const float4*)&Bs[kk][64 + tx*4];
#pragma unroll
      for (int r = 0; r < 8; ++r)
#pragma unroll
        for (int c = 0; c < 8; ++c)
          acc[r][c] = fmaf(a[r], b[c], acc[r][c]);
    }
    __syncthreads();
  }
  float sj[8];
#pragma unroll
  for (int c = 0; c < 4; ++c){
    sj[c]   = sqv[j0 + tx*4 + c];
    sj[c+4] = sqv[j0 + 64 + tx*4 + c];
  }
  float si[8];
#pragma unroll
  for (int r = 0; r < 8; ++r) si[r] = sqv[i0 + ty*8 + r];
  // finalize in-register
#pragma unroll
  for (int r = 0; r < 8; ++r)
#pragma unroll
    for (int c = 0; c < 8; ++c)
      acc[r][c] = 2.f*acc[r][c] - si[r] - sj[c];
  // normal store: rows i0+ty*8+r, col groups j0+tx*4 and j0+64+tx*4
#pragma unroll
  for (int r = 0; r < 8; ++r){
    float* drow = D + (size_t)(i0 + ty*8 + r)*NPTS;
    *(float4*)&drow[j0 + tx*4]      = make_float4(acc[r][0], acc[r][1], acc[r][2], acc[r][3]);
    *(float4*)&drow[j0 + 64 + tx*4] = make_float4(acc[r][4], acc[r][5], acc[r][6], acc[r][7]);
  }
  if (bj > bi){
    // mirror store: row j, cols i0+ty*8 .. +7
#pragma unroll
    for (int c = 0; c < 4; ++c){
      float* drow0 = D + (size_t)(j0 + tx*4 + c)*NPTS + i0 + ty*8;
      *(float4*)&drow0[0] = make_float4(acc[0][c], acc[1][c], acc[2][c], acc[3][c]);
      *(float4*)&drow0[4] = make_float4(acc[4][c], acc[5][c], acc[6][c], acc[7][c]);
      float* drow1 = D + (size_t)(j0 + 64 + tx*4 + c)*NPTS + i0 + ty*8;
      *(float4*)&drow1[0] = make_float4(acc[0][c+4], acc[1][c+4], acc[2][c+4], acc[3][c+4]);
      *(float4*)&drow1[4] = make_float4(acc[4][c+4], acc[5][c+4], acc[6][c+4], acc[7][c+4]);
    }
  }
}

// one wave per row: top-20 (value desc, tie -> lower index) distributed in lanes 0..19.
__global__ __launch_bounds__(256) void k_scan(const float* __restrict__ D,
                                              int* __restrict__ idx){
  const int lane = threadIdx.x & 63;
  const int wv   = threadIdx.x >> 6;
  const int row  = blockIdx.x*4 + wv;             // 0..4095 within batch
  const float* drow = D + (size_t)row*NPTS;
  float bv = -1e30f; int bi = -1;
  float thr = -1e30f;
  float dcur = drow[lane];
  for (int m0 = 0; m0 < NPTS; m0 += 64){
    float dnext = (m0 + 64 < NPTS) ? drow[m0 + 64 + lane] : -1e30f;
    unsigned long long mask = __ballot(dcur > thr);
    while (mask){
      int l = __ffsll(mask) - 1;
      mask &= mask - 1;
      float dv = __shfl(dcur, l);
      if (dv > thr){                               // uniform: thr may have risen
        float upv = __shfl_up(bv, 1);
        int   upi = __shfl_up(bi, 1);
        if (lane < KNN){
          bool ins  = dv > bv;                     // suffix mask (list sorted desc)
          bool insp = (lane > 0) && (dv > upv);
          if (ins){ bv = insp ? upv : dv; bi = insp ? upi : (m0 + l); }
        }
        thr = __shfl(bv, KNN-1);
      }
    }
    dcur = dnext;
  }
  if (lane < KNN) idx[(size_t)row*KNN + lane] = bi;
}

// Out(M x O) = X(M x Kdim, stride xstride) @ W^T (rows at stride wstride).
// BM=64, BO=64, BK=16, 256 threads, 4x4 micro-tile. [kk][row] LDS layout.
__global__ __launch_bounds__(256) void k_gemm_xw(const float* __restrict__ X, int xstride, int Kdim,
                                                 const float* __restrict__ W, int wstride,
                                                 float* __restrict__ Out, int ostride){
  __shared__ float Xs[16][68];
  __shared__ float Ws[16][68];
  const int m0 = blockIdx.x*64, o0 = blockIdx.y*64;
  const int tid = threadIdx.x, tx = tid & 15, ty = tid >> 4;
  float acc[4][4] = {};
  for (int k0 = 0; k0 < Kdim; k0 += 16){
#pragma unroll
    for (int i = 0; i < 4; ++i){
      int li = tid + 256*i;
      int row = li >> 4, kk = li & 15;
      bool ok = (k0 + kk) < Kdim;
      Xs[kk][row] = ok ? X[(size_t)(m0+row)*xstride + k0+kk] : 0.f;
      Ws[kk][row] = ok ? W[(size_t)(o0+row)*wstride + k0+kk] : 0.f;
    }
    __syncthreads();
#pragma unroll
    for (int kk = 0; kk < 16; ++kk){
      float xa[4], wb[4];
      *(float4*)xa = *(const float4*)&Xs[kk][ty*4];
      *(float4*)wb = *(const float4*)&Ws[kk][tx*4];
#pragma unroll
      for (int i = 0; i < 4; ++i)
#pragma unroll
        for (int j = 0; j < 4; ++j)
          acc[i][j] = fmaf(xa[i], wb[j], acc[i][j]);
    }
    __syncthreads();
  }
#pragma unroll
  for (int i = 0; i < 4; ++i){
    float4 v = make_float4(acc[i][0], acc[i][1], acc[i][2], acc[i][3]);
    *(float4*)&Out[(size_t)(m0+ty*4+i)*ostride + o0 + tx*4] = v;
  }
}

// out[n,o] = lrelu(scale*(red_k P[mk,o] - P[n,o] + Q[n,o]) + beta); red=max if scale>=0 else min
__global__ __launch_bounds__(256) void k_gather_conv(const float* __restrict__ P,
                                                     const float* __restrict__ Q,
                                                     const int* __restrict__ idx,
                                                     const float* __restrict__ g,
                                                     const float* __restrict__ bb,
                                                     const float* __restrict__ rm,
                                                     const float* __restrict__ rv,
                                                     float* __restrict__ Out, int oshift, int choff){
  const int O = 1 << oshift;
  int id = blockIdx.x*256 + threadIdx.x;
  int gn = id >> oshift;
  int o  = id & (O-1);
  int bbase = (gn >> 12) * NPTS;
  const int* ip = idx + (size_t)gn*KNN;
  float vmax = -1e30f, vmin = 1e30f;
#pragma unroll
  for (int k = 0; k < KNN; ++k){
    int m = ip[k];
    float v = P[((size_t)(bbase + m) << oshift) + o];
    vmax = fmaxf(vmax, v);
    vmin = fminf(vmin, v);
  }
  float scale = g[o] * rsqrtf(rv[o] + EPSBN);
  float beta  = bb[o] - rm[o]*scale;
  float R = (scale >= 0.f) ? vmax : vmin;
  float h = R - P[((size_t)gn << oshift) + o] + Q[((size_t)gn << oshift) + o];
  Out[(size_t)gn*512 + choff + o] = lrelu(fmaf(scale, h, beta));
}

// h = lrelu(bn(xc @ W5^T)) tile (128x128, 8x8 micro, split col groups),
// fused partial max/sum over rows.
__global__ __launch_bounds__(256) void k_gemm_w5_pool(const float* __restrict__ X,
                                                      const float* __restrict__ W,
                                                      const float* __restrict__ g,
                                                      const float* __restrict__ bb,
                                                      const float* __restrict__ rm,
                                                      const float* __restrict__ rv,
                                                      float* __restrict__ pmax,
                                                      float* __restrict__ psum){
  __shared__ float Xs[16][132];
  __shared__ float Ws[16][132];
  __shared__ float red[2][16][128];
  const int m0 = blockIdx.x*128, o0 = blockIdx.y*128;
  const int tid = threadIdx.x, tx = tid & 15, ty = tid >> 4;
  float acc[8][8] = {};
  for (int k0 = 0; k0 < 512; k0 += 16){
#pragma unroll
    for (int i = 0; i < 8; ++i){
      int li = tid + 256*i;
      int row = li >> 4, kk = li & 15;
      Xs[kk][row] = X[(size_t)(m0+row)*512 + k0+kk];
      Ws[kk][row] = W[(size_t)(o0+row)*512 + k0+kk];
    }
    __syncthreads();
#pragma unroll
    for (int kk = 0; kk < 16; ++kk){
      float xa[8], wb[8];
      *(float4*)&xa[0] = *(const float4*)&Xs[kk][ty*8];
      *(float4*)&xa[4] = *(const float4*)&Xs[kk][ty*8+4];
      *(float4*)&wb[0] = *(const float4*)&Ws[kk][tx*4];
      *(float4*)&wb[4] = *(const float4*)&Ws[kk][64 + tx*4];
#pragma unroll
      for (int i = 0; i < 8; ++i)
#pragma unroll
        for (int j = 0; j < 8; ++j)
          acc[i][j] = fmaf(xa[i], wb[j], acc[i][j]);
    }
    __syncthreads();
  }
#pragma unroll
  for (int j = 0; j < 8; ++j){
    int ocol = (j < 4) ? (tx*4 + j) : (64 + tx*4 + j - 4);
    int o = o0 + ocol;
    float scale = g[o] * rsqrtf(rv[o] + EPSBN);
    float beta  = bb[o] - rm[o]*scale;
    float mx = -1e30f, sm = 0.f;
#pragma unroll
    for (int i = 0; i < 8; ++i){
      float h = lrelu(fmaf(scale, acc[i][j], beta));
      mx = fmaxf(mx, h);
      sm += h;
    }
    red[0][ty][ocol] = mx;
    red[1][ty][ocol] = sm;
  }
  __syncthreads();
  if (tid < 128){
    float mx = -1e30f, sm = 0.f;
#pragma unroll
    for (int t = 0; t < 16; ++t){
      mx = fmaxf(mx, red[0][t][tid]);
      sm += red[1][t][tid];
    }
    pmax[(size_t)blockIdx.x*1024 + o0 + tid] = mx;
    psum[(size_t)blockIdx.x*1024 + o0 + tid] = sm;
  }
}

__global__ __launch_bounds__(256) void k_pool_reduce(const float* __restrict__ pmax,
                                                     const float* __restrict__ psum,
                                                     float* __restrict__ pooled){
  int id = blockIdx.x*256 + threadIdx.x;   // 8192
  int b = id >> 10, o = id & 1023;
  float mx = -1e30f, sm = 0.f;
  for (int t = 0; t < 32; ++t){
    mx = fmaxf(mx, pmax[(size_t)(b*32+t)*1024 + o]);
    sm += psum[(size_t)(b*32+t)*1024 + o];
  }
  pooled[(size_t)b*2048 + o] = mx;
  pooled[(size_t)b*2048 + 1024 + o] = sm * (1.f/NPTS);
}

__global__ __launch_bounds__(256) void k_fc1(const float* __restrict__ pooled,
                                             const float* __restrict__ W,
                                             const float* __restrict__ g,
                                             const float* __restrict__ bb,
                                             const float* __restrict__ rm,
                                             const float* __restrict__ rv,
                                             float* __restrict__ out){
  __shared__ float4 xs[512];
  int b = blockIdx.x >> 1;
  int o = ((blockIdx.x & 1) << 8) + threadIdx.x;
  const float4* pr = (const float4*)(pooled + (size_t)b*2048);
  for (int l = threadIdx.x; l < 512; l += 256) xs[l] = pr[l];
  __syncthreads();
  const float4* wr = (const float4*)(W + (size_t)o*2048);
  float s0=0.f, s1=0.f, s2=0.f, s3=0.f;
#pragma unroll 4
  for (int c = 0; c < 512; ++c){
    float4 w = wr[c], v = xs[c];
    s0 = fmaf(v.x, w.x, s0); s1 = fmaf(v.y, w.y, s1);
    s2 = fmaf(v.z, w.z, s2); s3 = fmaf(v.w, w.w, s3);
  }
  float h = (s0+s1)+(s2+s3);
  float scale = g[o] * rsqrtf(rv[o] + EPSBN);
  float beta  = bb[o] - rm[o]*scale;
  out[(size_t)b*512 + o] = lrelu(fmaf(scale, h, beta));
}

__global__ __launch_bounds__(256) void k_fc2(const float* __restrict__ in,
                                             const float* __restrict__ W,
                                             const float* __restrict__ bias,
                                             const float* __restrict__ g,
                                             const float* __restrict__ bb,
                                             const float* __restrict__ rm,
                                             const float* __restrict__ rv,
                                             float* __restrict__ out){
  __shared__ float4 xs[128];
  int b = blockIdx.x;
  int o = threadIdx.x;
  const float4* pr = (const float4*)(in + (size_t)b*512);
  if (threadIdx.x < 128) xs[threadIdx.x] = pr[threadIdx.x];
  __syncthreads();
  const float4* wr = (const float4*)(W + (size_t)o*512);
  float s0=0.f, s1=0.f, s2=0.f, s3=0.f;
#pragma unroll 4
  for (int c = 0; c < 128; ++c){
    float4 w = wr[c], v = xs[c];
    s0 = fmaf(v.x, w.x, s0); s1 = fmaf(v.y, w.y, s1);
    s2 = fmaf(v.z, w.z, s2); s3 = fmaf(v.w, w.w, s3);
  }
  float h = (s0+s1)+(s2+s3) + bias[o];
  float scale = g[o] * rsqrtf(rv[o] + EPSBN);
  float beta  = bb[o] - rm[o]*scale;
  out[(size_t)b*256 + o] = lrelu(fmaf(scale, h, beta));
}

__global__ __launch_bounds__(64) void k_fc3(const float* __restrict__ in,
                                            const float* __restrict__ W,
                                            const float* __restrict__ bias,
                                            float* __restrict__ out){
  int t = threadIdx.x;
  if (t >= 16) return;
  int b = t >> 1, o = t & 1;
  const float* xr = in + (size_t)b*256;
  const float* wr = W + (size_t)o*256;
  float s = 0.f;
  for (int c = 0; c < 256; ++c) s = fmaf(xr[c], wr[c], s);
  out[b*2 + o] = s + bias[o];
}

extern "C" void kernel_launch(void* const* d_in, const int* in_sizes, int n_in,
                              void* d_out, int out_size, void* d_ws, size_t ws_size,
                              hipStream_t stream){
  (void)in_sizes; (void)n_in; (void)out_size;
  const float* x   = (const float*)d_in[0];
  const float* W1  = (const float*)d_in[1];
  const float* g1  = (const float*)d_in[2];
  const float* b1  = (const float*)d_in[3];
  const float* m1  = (const float*)d_in[4];
  const float* v1  = (const float*)d_in[5];
  const float* W2  = (const float*)d_in[6];
  const float* g2  = (const float*)d_in[7];
  const float* b2  = (const float*)d_in[8];
  const float* m2  = (const float*)d_in[9];
  const float* v2  = (const float*)d_in[10];
  const float* W3  = (const float*)d_in[11];
  const float* g3  = (const float*)d_in[12];
  const float* b3  = (const float*)d_in[13];
  const float* m3  = (const float*)d_in[14];
  const float* v3  = (const float*)d_in[15];
  const float* W4  = (const float*)d_in[16];
  const float* g4  = (const float*)d_in[17];
  const float* b4  = (const float*)d_in[18];
  const float* m4  = (const float*)d_in[19];
  const float* v4  = (const float*)d_in[20];
  const float* W5  = (const float*)d_in[21];
  const float* g5  = (const float*)d_in[22];
  const float* b5  = (const float*)d_in[23];
  const float* m5  = (const float*)d_in[24];
  const float* v5  = (const float*)d_in[25];
  const float* L1  = (const float*)d_in[26];
  const float* gl1 = (const float*)d_in[27];
  const float* bl1 = (const float*)d_in[28];
  const float* ml1 = (const float*)d_in[29];
  const float* vl1 = (const float*)d_in[30];
  const float* L2  = (const float*)d_in[31];
  const float* L2b = (const float*)d_in[32];
  const float* gl2 = (const float*)d_in[33];
  const float* bl2 = (const float*)d_in[34];
  const float* vl2_g = (const float*)d_in[36];
  const float* ml2 = (const float*)d_in[35];
  const float* L3  = (const float*)d_in[37];
  const float* L3b = (const float*)d_in[38];

  // workspace layout (float offsets). Dbuf aliases P+Q (never live simultaneously).
  float* ws   = (float*)d_ws;
  float* xt   = ws;                      //   262144
  float* sq   = ws + 262144;             //    32768
  int*   idx  = (int*)(ws + 294912);     //   655360 ints
  float* Dbuf = ws + 950272;             // 16777216 (= P 8388608 + Q 8388608)
  float* P    = Dbuf;
  float* Q    = Dbuf + 8388608;
  float* xc   = ws + 17727488;           // 16777216  (8,4096,512) concat x1..x4
  float* pmax = ws + 34504704;           //   262144
  float* psum = ws + 34766848;           //   262144
  float* pool = ws + 35028992;           //    16384
  float* oA   = ws + 35045376;           //     4096
  float* oB   = ws + 35049472;           //     2048
  if (ws_size < (size_t)35051520 * 4) return;  // ~140 MB scratch

  k_transpose_pad<<<128, 256, 0, stream>>>(x, xt);

  // ---- edge conv 1: in xt (C=6 padded to 8), out xc[:,:,0:64] ----
  k_sqnorm<<<128, 256, 0, stream>>>(xt, 8, 2, sq);
  for (int b = 0; b < NB; ++b){
    k_dgemm<<<dim3(32,32), 256, 0, stream>>>(xt + (size_t)b*NPTS*8, 8, 8, sq + b*NPTS, Dbuf);
    k_scan<<<1024, 256, 0, stream>>>(Dbuf, idx + (size_t)b*NPTS*KNN);
  }
  k_gemm_xw<<<dim3(512,1), 256, 0, stream>>>(xt, 8, 6, W1,     12, P, 64);
  k_gemm_xw<<<dim3(512,1), 256, 0, stream>>>(xt, 8, 6, W1 + 6, 12, Q, 64);
  k_gather_conv<<<8192, 256, 0, stream>>>(P, Q, idx, g1, b1, m1, v1, xc, 6, 0);

  // ---- edge conv 2: in xc[:,:,0:64], out xc[:,:,64:128] ----
  k_sqnorm<<<128, 256, 0, stream>>>(xc, 512, 16, sq);
  for (int b = 0; b < NB; ++b){
    k_dgemm<<<dim3(32,32), 256, 0, stream>>>(xc + (size_t)b*NPTS*512, 512, 64, sq + b*NPTS, Dbuf);
    k_scan<<<1024, 256, 0, stream>>>(Dbuf, idx + (size_t)b*NPTS*KNN);
  }
  k_gemm_xw<<<dim3(512,1), 256, 0, stream>>>(xc, 512, 64, W2,      128, P, 64);
  k_gemm_xw<<<dim3(512,1), 256, 0, stream>>>(xc, 512, 64, W2 + 64, 128, Q, 64);
  k_gather_conv<<<8192, 256, 0, stream>>>(P, Q, idx, g2, b2, m2, v2, xc, 6, 64);

  // ---- edge conv 3: in xc[:,:,64:128], out xc[:,:,128:256] ----
  k_sqnorm<<<128, 256, 0, stream>>>(xc + 64, 512, 16, sq);
  for (int b = 0; b < NB; ++b){
    k_dgemm<<<dim3(32,32), 256, 0, stream>>>(xc + 64 + (size_t)b*NPTS*512, 512, 64, sq + b*NPTS, Dbuf);
    k_scan<<<1024, 256, 0, stream>>>(Dbuf, idx + (size_t)b*NPTS*KNN);
  }
  k_gemm_xw<<<dim3(512,2), 256, 0, stream>>>(xc + 64, 512, 64, W3,      128, P, 128);
  k_gemm_xw<<<dim3(512,2), 256, 0, stream>>>(xc + 64, 512, 64, W3 + 64, 128, Q, 128);
  k_gather_conv<<<16384, 256, 0, stream>>>(P, Q, idx, g3, b3, m3, v3, xc, 7, 128);

  // ---- edge conv 4: in xc[:,:,128:256], out xc[:,:,256:512] ----
  k_sqnorm<<<128, 256, 0, stream>>>(xc + 128, 512, 32, sq);
  for (int b = 0; b < NB; ++b){
    k_dgemm<<<dim3(32,32), 256, 0, stream>>>(xc + 128 + (size_t)b*NPTS*512, 512, 128, sq + b*NPTS, Dbuf);
    k_scan<<<1024, 256, 0, stream>>>(Dbuf, idx + (size_t)b*NPTS*KNN);
  }
  k_gemm_xw<<<dim3(512,4), 256, 0, stream>>>(xc + 128, 512, 128, W4,       256, P, 256);
  k_gemm_xw<<<dim3(512,4), 256, 0, stream>>>(xc + 128, 512, 128, W4 + 128, 256, Q, 256);
  k_gather_conv<<<32768, 256, 0, stream>>>(P, Q, idx, g4, b4, m4, v4, xc, 8, 256);

  // ---- global feature: h = lrelu(bn(xc @ W5^T)), max+mean pool over N ----
  k_gemm_w5_pool<<<dim3(256,8), 256, 0, stream>>>(xc, W5, g5, b5, m5, v5, pmax, psum);
  k_pool_reduce<<<32, 256, 0, stream>>>(pmax, psum, pool);

  // ---- classifier head ----
  k_fc1<<<16, 256, 0, stream>>>(pool, L1, gl1, bl1, ml1, vl1, oA);
  k_fc2<<<8, 256, 0, stream>>>(oA, L2, L2b, gl2, bl2, ml2, vl2_g, oB);
  k_fc3<<<1, 64, 0, stream>>>(oB, L3, L3b, (float*)d_out);
}

// Round 4
// 3324.809 us; speedup vs baseline: 1.0758x; 1.0758x over previous
//
#include <hip/hip_runtime.h>

// DGCNN forward, fp32 throughout.
// R4: fused kNN kernel (distance GEMM + per-row top-20 in one pass, no D
// materialization; 64 dispatches -> 4). P/Q conv GEMMs merged into one PQ GEMM
// per layer. Gather reads PQ interleaved rows.

#define NPTS   4096
#define NB     8
#define BNR    32768      // NB*NPTS
#define KNN    20
#define EPSBN  1e-5f
#define CAP    12         // per-row candidate buffer entries per merge round

__device__ __forceinline__ float lrelu(float x){ return x > 0.f ? x : 0.2f*x; }

// x (8,6,4096) -> xt (8,4096,8), channels 6,7 zero-padded
__global__ __launch_bounds__(256) void k_transpose_pad(const float* __restrict__ x,
                                                       float* __restrict__ xt){
  int id = blockIdx.x*256 + threadIdx.x;          // 0..32767
  int b = id >> 12, n = id & (NPTS-1);
  const float* xb = x + (size_t)b*6*NPTS + n;
  float* o = xt + (size_t)id*8;
#pragma unroll
  for (int c = 0; c < 6; ++c) o[c] = xb[(size_t)c*NPTS];
  o[6] = 0.f; o[7] = 0.f;
}

// squared norm per row (c4 float4 groups, row stride xstride floats)
__global__ __launch_bounds__(256) void k_sqnorm(const float* __restrict__ X, int xstride, int c4,
                                                float* __restrict__ sq){
  int id = blockIdx.x*256 + threadIdx.x;
  const float4* r = (const float4*)(X + (size_t)id*xstride);
  float s = 0.f;
  for (int c = 0; c < c4; ++c){ float4 v = r[c]; s += v.x*v.x + v.y*v.y + v.z*v.z + v.w*v.w; }
  sq[id] = s;
}

// Fused kNN: block = 64 rows of one batch, sweeps all 4096 cols in 128-col
// chunks. Distance tile in registers (4x8 micro); per-row top-20 in LDS via
// threshold filter + candidate buffer + owner merge (pending-mask retry loop
// guarantees correctness on buffer overflow).
template<int K>
__global__ __launch_bounds__(256) void k_knn_fused(const float* __restrict__ X, int xstride,
                                                   const float* __restrict__ sqv,
                                                   int* __restrict__ idx){
  constexpr int BK = (K < 32) ? K : 32;
  __shared__ float As[BK][68];      // A k-subtile: [kk][row]
  __shared__ float Bs[BK][132];     // B k-subtile: [kk][col]
  __shared__ float sqs[128];
  __shared__ float thr[64];
  __shared__ float lv[64][KNN];
  __shared__ int   li[64][KNN];
  __shared__ int   cnt[64];
  __shared__ float cv[64][CAP];
  __shared__ int   ci[64][CAP];

  const int b  = blockIdx.y;
  const int i0 = blockIdx.x * 64;
  const int tid = threadIdx.x, tx = tid & 15, ty = tid >> 4;
  const float* Xb  = X + (size_t)b * NPTS * xstride;
  const float* sqb = sqv + b * NPTS;

  if (tid < 64){
    thr[tid] = -3e38f; cnt[tid] = 0;
#pragma unroll
    for (int j = 0; j < KNN; ++j){ lv[tid][j] = -3e38f; li[tid][j] = 0; }
  }
  float sqi[4];
#pragma unroll
  for (int r = 0; r < 4; ++r) sqi[r] = sqb[i0 + ty*4 + r];

  for (int j0 = 0; j0 < NPTS; j0 += 128){
    float acc[4][8] = {};
    for (int k0 = 0; k0 < K; k0 += BK){
      // stage A: 64 rows x BK k  (row = tid&63, q = tid>>6 covers BK/4 k's)
      {
        int row = tid & 63, q = tid >> 6;
        const float* src = Xb + (size_t)(i0 + row)*xstride + k0;
#pragma unroll
        for (int k = q*(BK/4); k < (q+1)*(BK/4); ++k) As[k][row] = src[k];
      }
      // stage B: 128 cols x BK k  (col = tid&127, h = tid>>7 covers BK/2 k's)
      {
        int col = tid & 127, h = tid >> 7;
        const float* src = Xb + (size_t)(j0 + col)*xstride + k0;
#pragma unroll
        for (int k = h*(BK/2); k < (h+1)*(BK/2); ++k) Bs[k][col] = src[k];
      }
      if (k0 == 0 && tid < 128) sqs[tid] = sqb[j0 + tid];
      __syncthreads();
#pragma unroll
      for (int kk = 0; kk < BK; ++kk){
        float a[4], bb_[8];
        *(float4*)a        = *(const float4*)&As[kk][ty*4];
        *(float4*)&bb_[0]  = *(const float4*)&Bs[kk][tx*4];
        *(float4*)&bb_[4]  = *(const float4*)&Bs[kk][64 + tx*4];
#pragma unroll
        for (int r = 0; r < 4; ++r)
#pragma unroll
          for (int c = 0; c < 8; ++c)
            acc[r][c] = fmaf(a[r], bb_[c], acc[r][c]);
      }
      __syncthreads();
    }
    // candidate values: d = 2*acc - sq_i - sq_j (same fp order as R3 dgemm)
    float sq8[8];
#pragma unroll
    for (int c = 0; c < 4; ++c){ sq8[c] = sqs[tx*4 + c]; sq8[c+4] = sqs[64 + tx*4 + c]; }

    unsigned pending = 0xFFFFFFFFu;
    while (true){
      if (pending){
        float tr[4];
#pragma unroll
        for (int r = 0; r < 4; ++r) tr[r] = thr[ty*4 + r];
#pragma unroll
        for (int r = 0; r < 4; ++r)
#pragma unroll
          for (int c = 0; c < 8; ++c){
            unsigned bit = 1u << (r*8 + c);
            if (pending & bit){
              float val = 2.f*acc[r][c] - sqi[r] - sq8[c];
              if (val <= tr[r]) pending &= ~bit;
              else {
                int row = ty*4 + r;
                int pos = atomicAdd(&cnt[row], 1);
                if (pos < CAP){
                  int col = (c < 4) ? (j0 + tx*4 + c) : (j0 + 64 + tx*4 + c - 4);
                  cv[row][pos] = val; ci[row][pos] = col;
                  pending &= ~bit;
                }
              }
            }
          }
      }
      int any = __syncthreads_or(pending != 0u);
      if (tid < 64){
        int n = min(cnt[tid], CAP);
        for (int i2 = 0; i2 < n; ++i2){
          float val = cv[tid][i2]; int cc = ci[tid][i2];
          if (val > lv[tid][KNN-1]){
            int j = KNN-1;
            while (j > 0 && lv[tid][j-1] < val){
              lv[tid][j] = lv[tid][j-1]; li[tid][j] = li[tid][j-1]; --j;
            }
            lv[tid][j] = val; li[tid][j] = cc;
          }
        }
        thr[tid] = lv[tid][KNN-1];
        cnt[tid] = 0;
      }
      __syncthreads();
      if (!any) break;
    }
  }
  if (tid < 64){
    int gn = b*NPTS + i0 + tid;
#pragma unroll
    for (int j = 0; j < KNN; ++j) idx[(size_t)gn*KNN + j] = li[tid][j];
  }
}

// PQ(M x 2*Och) = X(M x Kdim) @ [Wa; Wb]^T where Wa=W[:, :Kdim], Wb=W[:, Kdim:2Kdim].
// BM=128, BO=64, BK=16, 8x4 micro.
__global__ __launch_bounds__(256) void k_gemm_pq(const float* __restrict__ X, int xstride, int Kdim,
                                                 const float* __restrict__ W, int wstride, int Och,
                                                 float* __restrict__ PQ){
  __shared__ float Xs[16][132];
  __shared__ float Ws[16][68];
  const int m0 = blockIdx.x*128, o0 = blockIdx.y*64;
  const int tid = threadIdx.x, tx = tid & 15, ty = tid >> 4;
  const int O2 = 2*Och;
  float acc[8][4] = {};
  for (int k0 = 0; k0 < Kdim; k0 += 16){
#pragma unroll
    for (int i = 0; i < 8; ++i){
      int li = tid + 256*i;
      int row = li >> 4, kk = li & 15;
      bool ok = (k0 + kk) < Kdim;
      Xs[kk][row] = ok ? X[(size_t)(m0+row)*xstride + k0+kk] : 0.f;
    }
#pragma unroll
    for (int i = 0; i < 4; ++i){
      int li = tid + 256*i;
      int row = li >> 4, kk = li & 15;
      int orow = o0 + row;
      const float* wr = (orow < Och) ? (W + (size_t)orow*wstride)
                                     : (W + (size_t)(orow-Och)*wstride + Kdim);
      bool ok = (k0 + kk) < Kdim;
      Ws[kk][row] = ok ? wr[k0+kk] : 0.f;
    }
    __syncthreads();
#pragma unroll
    for (int kk = 0; kk < 16; ++kk){
      float xa[8], wb[4];
      *(float4*)&xa[0] = *(const float4*)&Xs[kk][ty*8];
      *(float4*)&xa[4] = *(const float4*)&Xs[kk][ty*8+4];
      *(float4*)wb     = *(const float4*)&Ws[kk][tx*4];
#pragma unroll
      for (int i = 0; i < 8; ++i)
#pragma unroll
        for (int j = 0; j < 4; ++j)
          acc[i][j] = fmaf(xa[i], wb[j], acc[i][j]);
    }
    __syncthreads();
  }
#pragma unroll
  for (int i = 0; i < 8; ++i){
    float4 v = make_float4(acc[i][0], acc[i][1], acc[i][2], acc[i][3]);
    *(float4*)&PQ[(size_t)(m0+ty*8+i)*O2 + o0 + tx*4] = v;
  }
}

// out[n,o] = lrelu(scale*(red_k P[mk,o] - P[n,o] + Q[n,o]) + beta); red=max if scale>=0 else min
// P(m,o) = PQ[m*2O + o]; Q(n,o) = PQ[n*2O + O + o]
__global__ __launch_bounds__(256) void k_gather_conv(const float* __restrict__ PQ,
                                                     const int* __restrict__ idx,
                                                     const float* __restrict__ g,
                                                     const float* __restrict__ bb,
                                                     const float* __restrict__ rm,
                                                     const float* __restrict__ rv,
                                                     float* __restrict__ Out, int oshift, int choff){
  const int O = 1 << oshift;
  int id = blockIdx.x*256 + threadIdx.x;
  int gn = id >> oshift;
  int o  = id & (O-1);
  int bbase = (gn >> 12) * NPTS;
  const int* ip = idx + (size_t)gn*KNN;
  float vmax = -3e38f, vmin = 3e38f;
#pragma unroll
  for (int k = 0; k < KNN; ++k){
    int m = ip[k];
    float v = PQ[((size_t)(bbase + m) << (oshift+1)) + o];
    vmax = fmaxf(vmax, v);
    vmin = fminf(vmin, v);
  }
  float scale = g[o] * rsqrtf(rv[o] + EPSBN);
  float beta  = bb[o] - rm[o]*scale;
  float R = (scale >= 0.f) ? vmax : vmin;
  size_t self = (size_t)gn << (oshift+1);
  float h = R - PQ[self + o] + PQ[self + O + o];
  Out[(size_t)gn*512 + choff + o] = lrelu(fmaf(scale, h, beta));
}

// h = lrelu(bn(xc @ W5^T)) tile (128x128, 8x8 micro, split col groups),
// fused partial max/sum over rows.
__global__ __launch_bounds__(256) void k_gemm_w5_pool(const float* __restrict__ X,
                                                      const float* __restrict__ W,
                                                      const float* __restrict__ g,
                                                      const float* __restrict__ bb,
                                                      const float* __restrict__ rm,
                                                      const float* __restrict__ rv,
                                                      float* __restrict__ pmax,
                                                      float* __restrict__ psum){
  __shared__ float Xs[16][132];
  __shared__ float Ws[16][132];
  __shared__ float red[2][16][128];
  const int m0 = blockIdx.x*128, o0 = blockIdx.y*128;
  const int tid = threadIdx.x, tx = tid & 15, ty = tid >> 4;
  float acc[8][8] = {};
  for (int k0 = 0; k0 < 512; k0 += 16){
#pragma unroll
    for (int i = 0; i < 8; ++i){
      int li = tid + 256*i;
      int row = li >> 4, kk = li & 15;
      Xs[kk][row] = X[(size_t)(m0+row)*512 + k0+kk];
      Ws[kk][row] = W[(size_t)(o0+row)*512 + k0+kk];
    }
    __syncthreads();
#pragma unroll
    for (int kk = 0; kk < 16; ++kk){
      float xa[8], wb[8];
      *(float4*)&xa[0] = *(const float4*)&Xs[kk][ty*8];
      *(float4*)&xa[4] = *(const float4*)&Xs[kk][ty*8+4];
      *(float4*)&wb[0] = *(const float4*)&Ws[kk][tx*4];
      *(float4*)&wb[4] = *(const float4*)&Ws[kk][64 + tx*4];
#pragma unroll
      for (int i = 0; i < 8; ++i)
#pragma unroll
        for (int j = 0; j < 8; ++j)
          acc[i][j] = fmaf(xa[i], wb[j], acc[i][j]);
    }
    __syncthreads();
  }
#pragma unroll
  for (int j = 0; j < 8; ++j){
    int ocol = (j < 4) ? (tx*4 + j) : (64 + tx*4 + j - 4);
    int o = o0 + ocol;
    float scale = g[o] * rsqrtf(rv[o] + EPSBN);
    float beta  = bb[o] - rm[o]*scale;
    float mx = -3e38f, sm = 0.f;
#pragma unroll
    for (int i = 0; i < 8; ++i){
      float h = lrelu(fmaf(scale, acc[i][j], beta));
      mx = fmaxf(mx, h);
      sm += h;
    }
    red[0][ty][ocol] = mx;
    red[1][ty][ocol] = sm;
  }
  __syncthreads();
  if (tid < 128){
    float mx = -3e38f, sm = 0.f;
#pragma unroll
    for (int t = 0; t < 16; ++t){
      mx = fmaxf(mx, red[0][t][tid]);
      sm += red[1][t][tid];
    }
    pmax[(size_t)blockIdx.x*1024 + o0 + tid] = mx;
    psum[(size_t)blockIdx.x*1024 + o0 + tid] = sm;
  }
}

__global__ __launch_bounds__(256) void k_pool_reduce(const float* __restrict__ pmax,
                                                     const float* __restrict__ psum,
                                                     float* __restrict__ pooled){
  int id = blockIdx.x*256 + threadIdx.x;   // 8192
  int b = id >> 10, o = id & 1023;
  float mx = -3e38f, sm = 0.f;
  for (int t = 0; t < 32; ++t){
    mx = fmaxf(mx, pmax[(size_t)(b*32+t)*1024 + o]);
    sm += psum[(size_t)(b*32+t)*1024 + o];
  }
  pooled[(size_t)b*2048 + o] = mx;
  pooled[(size_t)b*2048 + 1024 + o] = sm * (1.f/NPTS);
}

__global__ __launch_bounds__(256) void k_fc1(const float* __restrict__ pooled,
                                             const float* __restrict__ W,
                                             const float* __restrict__ g,
                                             const float* __restrict__ bb,
                                             const float* __restrict__ rm,
                                             const float* __restrict__ rv,
                                             float* __restrict__ out){
  __shared__ float4 xs[512];
  int b = blockIdx.x >> 1;
  int o = ((blockIdx.x & 1) << 8) + threadIdx.x;
  const float4* pr = (const float4*)(pooled + (size_t)b*2048);
  for (int l = threadIdx.x; l < 512; l += 256) xs[l] = pr[l];
  __syncthreads();
  const float4* wr = (const float4*)(W + (size_t)o*2048);
  float s0=0.f, s1=0.f, s2=0.f, s3=0.f;
#pragma unroll 4
  for (int c = 0; c < 512; ++c){
    float4 w = wr[c], v = xs[c];
    s0 = fmaf(v.x, w.x, s0); s1 = fmaf(v.y, w.y, s1);
    s2 = fmaf(v.z, w.z, s2); s3 = fmaf(v.w, w.w, s3);
  }
  float h = (s0+s1)+(s2+s3);
  float scale = g[o] * rsqrtf(rv[o] + EPSBN);
  float beta  = bb[o] - rm[o]*scale;
  out[(size_t)b*512 + o] = lrelu(fmaf(scale, h, beta));
}

__global__ __launch_bounds__(256) void k_fc2(const float* __restrict__ in,
                                             const float* __restrict__ W,
                                             const float* __restrict__ bias,
                                             const float* __restrict__ g,
                                             const float* __restrict__ bb,
                                             const float* __restrict__ rm,
                                             const float* __restrict__ rv,
                                             float* __restrict__ out){
  __shared__ float4 xs[128];
  int b = blockIdx.x;
  int o = threadIdx.x;
  const float4* pr = (const float4*)(in + (size_t)b*512);
  if (threadIdx.x < 128) xs[threadIdx.x] = pr[threadIdx.x];
  __syncthreads();
  const float4* wr = (const float4*)(W + (size_t)o*512);
  float s0=0.f, s1=0.f, s2=0.f, s3=0.f;
#pragma unroll 4
  for (int c = 0; c < 128; ++c){
    float4 w = wr[c], v = xs[c];
    s0 = fmaf(v.x, w.x, s0); s1 = fmaf(v.y, w.y, s1);
    s2 = fmaf(v.z, w.z, s2); s3 = fmaf(v.w, w.w, s3);
  }
  float h = (s0+s1)+(s2+s3) + bias[o];
  float scale = g[o] * rsqrtf(rv[o] + EPSBN);
  float beta  = bb[o] - rm[o]*scale;
  out[(size_t)b*256 + o] = lrelu(fmaf(scale, h, beta));
}

__global__ __launch_bounds__(64) void k_fc3(const float* __restrict__ in,
                                            const float* __restrict__ W,
                                            const float* __restrict__ bias,
                                            float* __restrict__ out){
  int t = threadIdx.x;
  if (t >= 16) return;
  int b = t >> 1, o = t & 1;
  const float* xr = in + (size_t)b*256;
  const float* wr = W + (size_t)o*256;
  float s = 0.f;
  for (int c = 0; c < 256; ++c) s = fmaf(xr[c], wr[c], s);
  out[b*2 + o] = s + bias[o];
}

extern "C" void kernel_launch(void* const* d_in, const int* in_sizes, int n_in,
                              void* d_out, int out_size, void* d_ws, size_t ws_size,
                              hipStream_t stream){
  (void)in_sizes; (void)n_in; (void)out_size;
  const float* x   = (const float*)d_in[0];
  const float* W1  = (const float*)d_in[1];
  const float* g1  = (const float*)d_in[2];
  const float* b1  = (const float*)d_in[3];
  const float* m1  = (const float*)d_in[4];
  const float* v1  = (const float*)d_in[5];
  const float* W2  = (const float*)d_in[6];
  const float* g2  = (const float*)d_in[7];
  const float* b2  = (const float*)d_in[8];
  const float* m2  = (const float*)d_in[9];
  const float* v2  = (const float*)d_in[10];
  const float* W3  = (const float*)d_in[11];
  const float* g3  = (const float*)d_in[12];
  const float* b3  = (const float*)d_in[13];
  const float* m3  = (const float*)d_in[14];
  const float* v3  = (const float*)d_in[15];
  const float* W4  = (const float*)d_in[16];
  const float* g4  = (const float*)d_in[17];
  const float* b4  = (const float*)d_in[18];
  const float* m4  = (const float*)d_in[19];
  const float* v4  = (const float*)d_in[20];
  const float* W5  = (const float*)d_in[21];
  const float* g5  = (const float*)d_in[22];
  const float* b5  = (const float*)d_in[23];
  const float* m5  = (const float*)d_in[24];
  const float* v5  = (const float*)d_in[25];
  const float* L1  = (const float*)d_in[26];
  const float* gl1 = (const float*)d_in[27];
  const float* bl1 = (const float*)d_in[28];
  const float* ml1 = (const float*)d_in[29];
  const float* vl1 = (const float*)d_in[30];
  const float* L2  = (const float*)d_in[31];
  const float* L2b = (const float*)d_in[32];
  const float* gl2 = (const float*)d_in[33];
  const float* bl2 = (const float*)d_in[34];
  const float* ml2 = (const float*)d_in[35];
  const float* vl2 = (const float*)d_in[36];
  const float* L3  = (const float*)d_in[37];
  const float* L3b = (const float*)d_in[38];

  // workspace layout (float offsets)
  float* ws   = (float*)d_ws;
  float* xt   = ws;                      //   262144
  float* sq   = ws + 262144;             //    32768
  int*   idx  = (int*)(ws + 294912);     //   655360 ints
  float* PQ   = ws + 950272;             // 16777216 (max: 32768 x 512)
  float* xc   = ws + 17727488;           // 16777216  (8,4096,512) concat x1..x4
  float* pmax = ws + 34504704;           //   262144
  float* psum = ws + 34766848;           //   262144
  float* pool = ws + 35028992;           //    16384
  float* oA   = ws + 35045376;           //     4096
  float* oB   = ws + 35049472;           //     2048
  if (ws_size < (size_t)35051520 * 4) return;  // ~140 MB scratch

  k_transpose_pad<<<128, 256, 0, stream>>>(x, xt);

  // ---- edge conv 1: in xt (C=6 padded to 8), out xc[:,:,0:64] ----
  k_sqnorm<<<128, 256, 0, stream>>>(xt, 8, 2, sq);
  k_knn_fused<8><<<dim3(64,8), 256, 0, stream>>>(xt, 8, sq, idx);
  k_gemm_pq<<<dim3(256,2), 256, 0, stream>>>(xt, 8, 6, W1, 12, 64, PQ);
  k_gather_conv<<<8192, 256, 0, stream>>>(PQ, idx, g1, b1, m1, v1, xc, 6, 0);

  // ---- edge conv 2: in xc[:,:,0:64], out xc[:,:,64:128] ----
  k_sqnorm<<<128, 256, 0, stream>>>(xc, 512, 16, sq);
  k_knn_fused<64><<<dim3(64,8), 256, 0, stream>>>(xc, 512, sq, idx);
  k_gemm_pq<<<dim3(256,2), 256, 0, stream>>>(xc, 512, 64, W2, 128, 64, PQ);
  k_gather_conv<<<8192, 256, 0, stream>>>(PQ, idx, g2, b2, m2, v2, xc, 6, 64);

  // ---- edge conv 3: in xc[:,:,64:128], out xc[:,:,128:256] ----
  k_sqnorm<<<128, 256, 0, stream>>>(xc + 64, 512, 16, sq);
  k_knn_fused<64><<<dim3(64,8), 256, 0, stream>>>(xc + 64, 512, sq, idx);
  k_gemm_pq<<<dim3(256,4), 256, 0, stream>>>(xc + 64, 512, 64, W3, 128, 128, PQ);
  k_gather_conv<<<16384, 256, 0, stream>>>(PQ, idx, g3, b3, m3, v3, xc, 7, 128);

  // ---- edge conv 4: in xc[:,:,128:256], out xc[:,:,256:512] ----
  k_sqnorm<<<128, 256, 0, stream>>>(xc + 128, 512, 32, sq);
  k_knn_fused<128><<<dim3(64,8), 256, 0, stream>>>(xc + 128, 512, sq, idx);
  k_gemm_pq<<<dim3(256,8), 256, 0, stream>>>(xc + 128, 512, 128, W4, 256, 256, PQ);
  k_gather_conv<<<32768, 256, 0, stream>>>(PQ, idx, g4, b4, m4, v4, xc, 8, 256);

  // ---- global feature: h = lrelu(bn(xc @ W5^T)), max+mean pool over N ----
  k_gemm_w5_pool<<<dim3(256,8), 256, 0, stream>>>(xc, W5, g5, b5, m5, v5, pmax, psum);
  k_pool_reduce<<<32, 256, 0, stream>>>(pmax, psum, pool);

  // ---- classifier head ----
  k_fc1<<<16, 256, 0, stream>>>(pool, L1, gl1, bl1, ml1, vl1, oA);
  k_fc2<<<8, 256, 0, stream>>>(oA, L2, L2b, gl2, bl2, ml2, vl2, oB);
  k_fc3<<<1, 64, 0, stream>>>(oB, L3, L3b, (float*)d_out);
}